// Round 5
// baseline (395.741 us; speedup 1.0000x reference)
//
#include <hip/hip_runtime.h>

#define D 128
#define SCH 1024  // scan elems per block

typedef __attribute__((ext_vector_type(8))) short short8;
typedef __attribute__((ext_vector_type(4))) float floatx4;

// RNE split of fp32 into bf16 hi + bf16 lo (x ~= hi + lo, err ~2^-17 |x|)
__device__ inline void bf16split(float x, ushort& hi, ushort& lo) {
  unsigned u = __float_as_uint(x);
  unsigned rh = (u + 0x7FFFu + ((u >> 16) & 1u)) & 0xFFFF0000u;
  hi = (ushort)(rh >> 16);
  float fl = x - __uint_as_float(rh);
  unsigned ul = __float_as_uint(fl);
  lo = (ushort)((ul + 0x7FFFu + ((ul >> 16) & 1u)) >> 16);
}

// NT load/store via ext_vector_type (builtin rejects HIP_vector_type structs)
__device__ inline float4 ntload4(const float* p) {
  floatx4 v = __builtin_nontemporal_load((const floatx4*)p);
  return make_float4(v.x, v.y, v.z, v.w);
}
__device__ inline void ntstore4(float* p, float4 v) {
  floatx4 u = {v.x, v.y, v.z, v.w};
  __builtin_nontemporal_store(u, (floatx4*)p);
}

// K0: block 0: gvec = globals @ W3 + b3 (2-way k-split); block 1: zero an
__global__ void k_gproj(const float* __restrict__ g, const float* __restrict__ W3,
                        const float* __restrict__ b3, float* __restrict__ gvec,
                        float* __restrict__ an) {
  if (blockIdx.x == 1) {
    if (threadIdx.x < D) an[threadIdx.x] = 0.f;
    return;
  }
  __shared__ float part[256];
  const int j = threadIdx.x & 127, half = threadIdx.x >> 7;
  float acc = 0.f;
  for (int k = half * 64; k < half * 64 + 64; ++k)
    acc = fmaf(g[k], W3[k * D + j], acc);
  part[threadIdx.x] = acc;
  __syncthreads();
  if (threadIdx.x < D) gvec[j] = b3[j] + part[j] + part[j + 128];
}

// K1: degree histograms
__global__ void k_degrees(const int* __restrict__ snd, const int* __restrict__ rcv,
                          int* __restrict__ cs, int* __restrict__ cr, int E) {
  const int e = blockIdx.x * blockDim.x + threadIdx.x;
  if (e < E) {
    atomicAdd(cs + snd[e], 1);
    atomicAdd(cr + rcv[e], 1);
  }
}

// K2a: per-block sums (guards at int4 granularity)
__global__ void k_scanA(const int* __restrict__ cnt, int* __restrict__ bsum, int n) {
  __shared__ int red[4];
  const int t = threadIdx.x;
  const int base = blockIdx.x * SCH + t * 4;
  int4 v = make_int4(0, 0, 0, 0);
  if (base < n) v = *(const int4*)(cnt + base);
  int s = v.x + v.y + v.z + v.w;
#pragma unroll
  for (int o = 32; o > 0; o >>= 1) s += __shfl_down(s, o, 64);
  if ((t & 63) == 0) red[t >> 6] = s;
  __syncthreads();
  if (t == 0) bsum[blockIdx.x] = red[0] + red[1] + red[2] + red[3];
}

// K2b: single tiny block scans the per-block sums (nb <= 256)
__global__ void k_scanB(const int* __restrict__ bsum, int* __restrict__ bbase, int nb) {
  __shared__ int sh[256];
  const int t = threadIdx.x;
  const int v = (t < nb) ? bsum[t] : 0;
  sh[t] = v;
  __syncthreads();
  for (int st = 1; st < 256; st <<= 1) {
    const int u = (t >= st) ? sh[t - st] : 0;
    __syncthreads();
    sh[t] += u;
    __syncthreads();
  }
  if (t < nb) bbase[t] = sh[t] - v;  // exclusive
}

// K2c: per-block exclusive scan + global base -> off, cursor
__global__ void k_scanC(const int* __restrict__ cnt, const int* __restrict__ bbase,
                        int* __restrict__ off, int* __restrict__ cursor, int n) {
  __shared__ int sh[256];
  const int t = threadIdx.x;
  const int base = blockIdx.x * SCH + t * 4;
  int4 v = make_int4(0, 0, 0, 0);
  if (base < n) v = *(const int4*)(cnt + base);
  const int s = v.x + v.y + v.z + v.w;
  sh[t] = s;
  __syncthreads();
  for (int st = 1; st < 256; st <<= 1) {
    const int u = (t >= st) ? sh[t - st] : 0;
    __syncthreads();
    sh[t] += u;
    __syncthreads();
  }
  const int ex = sh[t] - s + bbase[blockIdx.x];
  if (base < n) {
    const int4 o = make_int4(ex, ex + v.x, ex + v.x + v.y, ex + v.x + v.y + v.z);
    *(int4*)(off + base) = o;
    *(int4*)(cursor + base) = o;
  }
}

// K3: CSR fill (bucket edges by receiver)
__global__ void k_fill(const int* __restrict__ snd, const int* __restrict__ rcv,
                       int* __restrict__ cursor, int* __restrict__ srt, int E) {
  const int e = blockIdx.x * blockDim.x + threadIdx.x;
  if (e < E) {
    const int p = atomicAdd(cursor + rcv[e], 1);
    srt[p] = snd[e];
  }
}

// K3b: precompute W^T split to bf16 hi/lo: wt[mat(2)][hi/lo(2)][n(128)][k(128)]
__global__ void k_wsplit(const float* __restrict__ W1, const float* __restrict__ W2,
                         ushort* __restrict__ wt) {
  const int id = blockIdx.x * blockDim.x + threadIdx.x;  // 2*16384
  const int mat = id >> 14;
  const int idx = id & 16383;
  const int k = idx >> 7;
  const int n = idx & 127;
  const float x = (mat ? W2 : W1)[k * D + n];
  ushort hi, lo;
  bf16split(x, hi, lo);
  wt[(size_t)mat * 32768 + (size_t)n * 128 + k] = hi;
  wt[(size_t)mat * 32768 + 16384 + (size_t)n * 128 + k] = lo;
}

// K4: merged bf16x3 MFMA dual GEMM: one 64x256 tile computes [h1 | conv].
// 4 waves, wave w owns cols w*64..w*64+63 (w<2 -> h1/W1, w>=2 -> conv/W2).
// BK=32, 4 K-passes; LDS rows padded to stride 40 ushorts (80 B) -> 2-way-free
// banks for both ushort4 staging writes and b128 frag reads; A staged/split ONCE.
__global__ __launch_bounds__(256, 3) void k_gemm(
    const float* __restrict__ A, const ushort* __restrict__ wt,
    const float* __restrict__ b1, const float* __restrict__ b2,
    const float* __restrict__ gvec, const int* __restrict__ cnt_send,
    float* __restrict__ outH, float* __restrict__ conv, int n) {
  __shared__ ushort Ah[64 * 40], Al[64 * 40], Wh[256 * 40], Wl[256 * 40];
  const int t = threadIdx.x;
  const int row0 = blockIdx.x * 64;
  const int lane = t & 63, w = t >> 6;
  const int m = lane & 15, quad = lane >> 4;

  floatx4 acc[4][4];
#pragma unroll
  for (int i = 0; i < 4; ++i)
#pragma unroll
    for (int j = 0; j < 4; ++j) acc[i][j] = (floatx4)0.f;

  const int arow = t >> 2, akl = (t & 3) * 8;  // A staging coords
  const int wcol = t;                          // W staging coord
  const int wmat = wcol >> 7, wn = wcol & 127;

  for (int p = 0; p < 4; ++p) {
    // --- stage A (64 rows x 32 k fp32 -> bf16 hi/lo), read A exactly once ---
    {
      const int grow = row0 + arow;
      const bool ok = grow < n;
      const float* gp = A + (size_t)grow * D + p * 32 + akl;
      float4 v0 = make_float4(0.f, 0.f, 0.f, 0.f), v1 = v0;
      if (ok) {
        v0 = *(const float4*)gp;
        v1 = *(const float4*)(gp + 4);
      }
      ushort h0, l0, h1, l1, h2, l2, h3, l3;
      const int a = arow * 40 + akl;
      bf16split(v0.x, h0, l0); bf16split(v0.y, h1, l1);
      bf16split(v0.z, h2, l2); bf16split(v0.w, h3, l3);
      *(ushort4*)&Ah[a] = make_ushort4(h0, h1, h2, h3);
      *(ushort4*)&Al[a] = make_ushort4(l0, l1, l2, l3);
      bf16split(v1.x, h0, l0); bf16split(v1.y, h1, l1);
      bf16split(v1.z, h2, l2); bf16split(v1.w, h3, l3);
      *(ushort4*)&Ah[a + 4] = make_ushort4(h0, h1, h2, h3);
      *(ushort4*)&Al[a + 4] = make_ushort4(l0, l1, l2, l3);
    }
    // --- stage W' slab (256 cols x 32 k bf16 hi/lo from precomputed wt) ---
    {
      const ushort* gh = wt + (size_t)wmat * 32768 + (size_t)wn * 128 + p * 32;
      const ushort* gl = gh + 16384;
      const int a = wcol * 40;
#pragma unroll
      for (int c = 0; c < 4; ++c) {
        *(uint4*)&Wh[a + 8 * c] = *(const uint4*)(gh + 8 * c);
        *(uint4*)&Wl[a + 8 * c] = *(const uint4*)(gl + 8 * c);
      }
    }
    __syncthreads();
    short8 a_h[4], a_l[4];
#pragma unroll
    for (int i = 0; i < 4; ++i) {
      const int r = (i * 16 + m) * 40 + quad * 8;
      a_h[i] = *(const short8*)&Ah[r];
      a_l[i] = *(const short8*)&Al[r];
    }
#pragma unroll
    for (int j = 0; j < 4; ++j) {
      const int r = (w * 64 + j * 16 + m) * 40 + quad * 8;
      const short8 b_h = *(const short8*)&Wh[r];
      const short8 b_l = *(const short8*)&Wl[r];
#pragma unroll
      for (int i = 0; i < 4; ++i) {
        floatx4 c = acc[i][j];
        c = __builtin_amdgcn_mfma_f32_16x16x32_bf16(a_h[i], b_h, c, 0, 0, 0);
        c = __builtin_amdgcn_mfma_f32_16x16x32_bf16(a_h[i], b_l, c, 0, 0, 0);
        c = __builtin_amdgcn_mfma_f32_16x16x32_bf16(a_l[i], b_h, c, 0, 0, 0);
        acc[i][j] = c;
      }
    }
    __syncthreads();
  }

  // --- epilogue: C/D layout col=lane&15, row=quad*4+reg; branch is wave-uniform ---
  if (w < 2) {
    float bb[4], gg[4];
#pragma unroll
    for (int j = 0; j < 4; ++j) {
      const int col = w * 64 + j * 16 + m;
      bb[j] = b1[col];
      gg[j] = gvec[col];
    }
#pragma unroll
    for (int i = 0; i < 4; ++i)
#pragma unroll
      for (int pp = 0; pp < 4; ++pp) {
        const int rg = row0 + i * 16 + quad * 4 + pp;
        if (rg >= n) continue;
#pragma unroll
        for (int j = 0; j < 4; ++j) {
          const int col = w * 64 + j * 16 + m;
          outH[(size_t)rg * D + col] = acc[i][j][pp] + bb[j] + gg[j];
        }
      }
  } else {
    float bb[4];
#pragma unroll
    for (int j = 0; j < 4; ++j) bb[j] = b2[(w - 2) * 64 + j * 16 + m];
#pragma unroll
    for (int i = 0; i < 4; ++i)
#pragma unroll
      for (int pp = 0; pp < 4; ++pp) {
        const int rg = row0 + i * 16 + quad * 4 + pp;
        if (rg >= n) continue;
        const float sc = rsqrtf(fmaxf((float)cnt_send[rg], 1.f));
#pragma unroll
        for (int j = 0; j < 4; ++j) {
          const int col = (w - 2) * 64 + j * 16 + m;
          conv[(size_t)rg * D + col] = (acc[i][j][pp] + bb[j]) * sc;
        }
      }
  }
}

// K5: pull aggregation + fused epilogue. Half-wave per row, masked unroll-8
// gathers. Single-use streams (h1, nodes reads; h writes) use NT hints so L3
// stays dedicated to the conv gather working set.
__global__ __launch_bounds__(256) void k_agg_finalize(
    const float* __restrict__ conv, const int* __restrict__ off,
    const int* __restrict__ cnt_recv, const int* __restrict__ srt,
    const float* __restrict__ nodes, float* __restrict__ h,
    float* __restrict__ an, int n) {
  __shared__ float anl[8][D];
  const int hw = threadIdx.x >> 5;
  const int ln = threadIdx.x & 31;
  const int ghw = blockIdx.x * 8 + hw;
  const int nhw = gridDim.x * 8;
  const int c0 = ln * 4;

  float a0 = 0.f, a1 = 0.f, a2 = 0.f, a3 = 0.f;
  for (int r = ghw; r < n; r += nhw) {
    const int dg = cnt_recv[r];
    const int o = off[r];
    const float4 h1 = ntload4(h + (size_t)r * D + c0);
    const float4 nd = ntload4(nodes + (size_t)r * D + c0);
    float sx = 0.f, sy = 0.f, sz = 0.f, sw = 0.f;
    for (int i = 0; i < dg; i += 8) {
      int idx[8];
      float mk[8];
#pragma unroll
      for (int j = 0; j < 8; ++j) {
        const int p = i + j;
        const bool v = p < dg;
        idx[j] = srt[o + (v ? p : 0)];
        mk[j] = v ? 1.f : 0.f;
      }
      float4 c[8];
#pragma unroll
      for (int j = 0; j < 8; ++j)
        c[j] = *(const float4*)(conv + (size_t)idx[j] * D + c0);
#pragma unroll
      for (int j = 0; j < 8; ++j) {
        sx = fmaf(mk[j], c[j].x, sx);
        sy = fmaf(mk[j], c[j].y, sy);
        sz = fmaf(mk[j], c[j].z, sz);
        sw = fmaf(mk[j], c[j].w, sw);
      }
    }
    const float sc = rsqrtf(fmaxf((float)dg, 1.f));
    const float x0 = fmaxf(h1.x + sx * sc, 0.f) + nd.x;
    const float x1 = fmaxf(h1.y + sy * sc, 0.f) + nd.y;
    const float x2 = fmaxf(h1.z + sz * sc, 0.f) + nd.z;
    const float x3 = fmaxf(h1.w + sw * sc, 0.f) + nd.w;
    ntstore4(h + (size_t)r * D + c0, make_float4(x0, x1, x2, x3));
    a0 += x0; a1 += x1; a2 += x2; a3 += x3;
  }
  anl[hw][c0 + 0] = a0;
  anl[hw][c0 + 1] = a1;
  anl[hw][c0 + 2] = a2;
  anl[hw][c0 + 3] = a3;
  __syncthreads();
  if (threadIdx.x < D) {
    float s = 0.f;
#pragma unroll
    for (int k = 0; k < 8; ++k) s += anl[k][threadIdx.x];
    atomicAdd(an + threadIdx.x, s);
  }
}

// K6: g_new = globals + relu(concat([an, globals]) @ Wg + bg), 2-way k-split
__global__ void k_gupdate(const float* __restrict__ an, const float* __restrict__ g,
                          const float* __restrict__ Wg, const float* __restrict__ bg,
                          float* __restrict__ gout) {
  __shared__ float part[256];
  const int j = threadIdx.x & 127, half = threadIdx.x >> 7;
  float acc = 0.f;
  if (half == 0) {
    for (int k = 0; k < D; ++k) acc = fmaf(an[k], Wg[k * D + j], acc);
  } else {
    for (int k = 0; k < D; ++k) acc = fmaf(g[k], Wg[(D + k) * D + j], acc);
  }
  part[threadIdx.x] = acc;
  __syncthreads();
  if (threadIdx.x < D)
    gout[j] = g[j] + fmaxf(bg[j] + part[j] + part[j + 128], 0.f);
}

extern "C" void kernel_launch(void* const* d_in, const int* in_sizes, int n_in,
                              void* d_out, int out_size, void* d_ws, size_t ws_size,
                              hipStream_t stream) {
  const float* nodes = (const float*)d_in[0];
  const float* globals_ = (const float*)d_in[1];
  const int* senders = (const int*)d_in[2];
  const int* receivers = (const int*)d_in[3];
  const float* W1_w = (const float*)d_in[4];
  const float* W1_b = (const float*)d_in[5];
  const float* W2_w = (const float*)d_in[6];
  const float* W2_b = (const float*)d_in[7];
  const float* W3_w = (const float*)d_in[8];
  const float* W3_b = (const float*)d_in[9];
  const float* Wg_w = (const float*)d_in[10];
  const float* Wg_b = (const float*)d_in[11];
  const int N = in_sizes[0] / D;
  const int E = in_sizes[2];
  const int nb = (N + SCH - 1) / SCH;

  float* h = (float*)d_out;
  float* gout = h + (size_t)N * D;

  float* ws = (float*)d_ws;
  float* conv = ws;                            // N*D floats
  int* cnt_send = (int*)(ws + (size_t)N * D);  // N
  int* cnt_recv = cnt_send + N;                // N
  int* off = cnt_recv + N;                     // N
  int* cursor = off + N;                       // N (dead after k_fill -> wt)
  int* srt = cursor + N;                       // E
  float* gvec = (float*)(srt + E);             // D
  float* an = gvec + D;                        // D
  int* bsum = (int*)(an + D);                  // nb
  int* bbase = bsum + 256;                     // nb
  ushort* wt = (ushort*)cursor;                // 128 KB, reused after k_fill

  (void)hipMemsetAsync(cnt_send, 0, 2 * (size_t)N * sizeof(int), stream);

  hipLaunchKernelGGL(k_gproj, dim3(2), dim3(256), 0, stream, globals_, W3_w, W3_b,
                     gvec, an);
  hipLaunchKernelGGL(k_degrees, dim3((E + 255) / 256), dim3(256), 0, stream,
                     senders, receivers, cnt_send, cnt_recv, E);
  hipLaunchKernelGGL(k_scanA, dim3(nb), dim3(256), 0, stream, cnt_recv, bsum, N);
  hipLaunchKernelGGL(k_scanB, dim3(1), dim3(256), 0, stream, bsum, bbase, nb);
  hipLaunchKernelGGL(k_scanC, dim3(nb), dim3(256), 0, stream, cnt_recv, bbase,
                     off, cursor, N);
  hipLaunchKernelGGL(k_fill, dim3((E + 255) / 256), dim3(256), 0, stream,
                     senders, receivers, cursor, srt, E);
  hipLaunchKernelGGL(k_wsplit, dim3(128), dim3(256), 0, stream, W1_w, W2_w, wt);
  hipLaunchKernelGGL(k_gemm, dim3((N + 63) / 64), dim3(256), 0, stream,
                     nodes, wt, W1_b, W2_b, gvec, cnt_send, h, conv, N);
  hipLaunchKernelGGL(k_agg_finalize, dim3(4096), dim3(256), 0, stream,
                     conv, off, cnt_recv, srt, nodes, h, an, N);
  hipLaunchKernelGGL(k_gupdate, dim3(1), dim3(256), 0, stream, an, globals_,
                     Wg_w, Wg_b, gout);
}

// Round 6
// 371.333 us; speedup vs baseline: 1.0657x; 1.0657x over previous
//
#include <hip/hip_runtime.h>

#define D 128
#define SCH 1024  // scan elems per block

typedef __attribute__((ext_vector_type(8))) short short8;
typedef __attribute__((ext_vector_type(4))) float floatx4;

// RNE split of fp32 into bf16 hi + bf16 lo (x ~= hi + lo, err ~2^-17 |x|)
__device__ inline void bf16split(float x, ushort& hi, ushort& lo) {
  unsigned u = __float_as_uint(x);
  unsigned rh = (u + 0x7FFFu + ((u >> 16) & 1u)) & 0xFFFF0000u;
  hi = (ushort)(rh >> 16);
  float fl = x - __uint_as_float(rh);
  unsigned ul = __float_as_uint(fl);
  lo = (ushort)((ul + 0x7FFFu + ((ul >> 16) & 1u)) >> 16);
}

// K0: block 0: gvec = globals @ W3 + b3 (2-way k-split); block 1: zero an
__global__ void k_gproj(const float* __restrict__ g, const float* __restrict__ W3,
                        const float* __restrict__ b3, float* __restrict__ gvec,
                        float* __restrict__ an) {
  if (blockIdx.x == 1) {
    if (threadIdx.x < D) an[threadIdx.x] = 0.f;
    return;
  }
  __shared__ float part[256];
  const int j = threadIdx.x & 127, half = threadIdx.x >> 7;
  float acc = 0.f;
  for (int k = half * 64; k < half * 64 + 64; ++k)
    acc = fmaf(g[k], W3[k * D + j], acc);
  part[threadIdx.x] = acc;
  __syncthreads();
  if (threadIdx.x < D) gvec[j] = b3[j] + part[j] + part[j + 128];
}

// K1: degree histograms
__global__ void k_degrees(const int* __restrict__ snd, const int* __restrict__ rcv,
                          int* __restrict__ cs, int* __restrict__ cr, int E) {
  const int e = blockIdx.x * blockDim.x + threadIdx.x;
  if (e < E) {
    atomicAdd(cs + snd[e], 1);
    atomicAdd(cr + rcv[e], 1);
  }
}

// K2a: per-block sums (guards at int4 granularity)
__global__ void k_scanA(const int* __restrict__ cnt, int* __restrict__ bsum, int n) {
  __shared__ int red[4];
  const int t = threadIdx.x;
  const int base = blockIdx.x * SCH + t * 4;
  int4 v = make_int4(0, 0, 0, 0);
  if (base < n) v = *(const int4*)(cnt + base);
  int s = v.x + v.y + v.z + v.w;
#pragma unroll
  for (int o = 32; o > 0; o >>= 1) s += __shfl_down(s, o, 64);
  if ((t & 63) == 0) red[t >> 6] = s;
  __syncthreads();
  if (t == 0) bsum[blockIdx.x] = red[0] + red[1] + red[2] + red[3];
}

// K2b: single tiny block scans the per-block sums (nb <= 256)
__global__ void k_scanB(const int* __restrict__ bsum, int* __restrict__ bbase, int nb) {
  __shared__ int sh[256];
  const int t = threadIdx.x;
  const int v = (t < nb) ? bsum[t] : 0;
  sh[t] = v;
  __syncthreads();
  for (int st = 1; st < 256; st <<= 1) {
    const int u = (t >= st) ? sh[t - st] : 0;
    __syncthreads();
    sh[t] += u;
    __syncthreads();
  }
  if (t < nb) bbase[t] = sh[t] - v;  // exclusive
}

// K2c: per-block exclusive scan + global base -> off, cursor
__global__ void k_scanC(const int* __restrict__ cnt, const int* __restrict__ bbase,
                        int* __restrict__ off, int* __restrict__ cursor, int n) {
  __shared__ int sh[256];
  const int t = threadIdx.x;
  const int base = blockIdx.x * SCH + t * 4;
  int4 v = make_int4(0, 0, 0, 0);
  if (base < n) v = *(const int4*)(cnt + base);
  const int s = v.x + v.y + v.z + v.w;
  sh[t] = s;
  __syncthreads();
  for (int st = 1; st < 256; st <<= 1) {
    const int u = (t >= st) ? sh[t - st] : 0;
    __syncthreads();
    sh[t] += u;
    __syncthreads();
  }
  const int ex = sh[t] - s + bbase[blockIdx.x];
  if (base < n) {
    const int4 o = make_int4(ex, ex + v.x, ex + v.x + v.y, ex + v.x + v.y + v.z);
    *(int4*)(off + base) = o;
    *(int4*)(cursor + base) = o;
  }
}

// K3: CSR fill (bucket edges by receiver)
__global__ void k_fill(const int* __restrict__ snd, const int* __restrict__ rcv,
                       int* __restrict__ cursor, int* __restrict__ srt, int E) {
  const int e = blockIdx.x * blockDim.x + threadIdx.x;
  if (e < E) {
    const int p = atomicAdd(cursor + rcv[e], 1);
    srt[p] = snd[e];
  }
}

// K3b: precompute W^T split to bf16 hi/lo: wt[mat(2)][hi/lo(2)][n(128)][k(128)]
__global__ void k_wsplit(const float* __restrict__ W1, const float* __restrict__ W2,
                         ushort* __restrict__ wt) {
  const int id = blockIdx.x * blockDim.x + threadIdx.x;  // 2*16384
  const int mat = id >> 14;
  const int idx = id & 16383;
  const int k = idx >> 7;
  const int n = idx & 127;
  const float x = (mat ? W2 : W1)[k * D + n];
  ushort hi, lo;
  bf16split(x, hi, lo);
  wt[(size_t)mat * 32768 + (size_t)n * 128 + k] = hi;
  wt[(size_t)mat * 32768 + 16384 + (size_t)n * 128 + k] = lo;
}

// K4: merged bf16x3 MFMA dual GEMM: one 64x256 tile computes [h1 | conv].
// 4 waves, wave w owns cols w*64..w*64+63 (w<2 -> h1/W1, w>=2 -> conv/W2).
// BK=32, 4 K-passes; LDS rows padded to stride 40 ushorts (80 B) -> 2-way-free
// banks for both ushort4 staging writes and b128 frag reads; A staged/split ONCE.
__global__ __launch_bounds__(256, 3) void k_gemm(
    const float* __restrict__ A, const ushort* __restrict__ wt,
    const float* __restrict__ b1, const float* __restrict__ b2,
    const float* __restrict__ gvec, const int* __restrict__ cnt_send,
    float* __restrict__ outH, float* __restrict__ conv, int n) {
  __shared__ ushort Ah[64 * 40], Al[64 * 40], Wh[256 * 40], Wl[256 * 40];
  const int t = threadIdx.x;
  const int row0 = blockIdx.x * 64;
  const int lane = t & 63, w = t >> 6;
  const int m = lane & 15, quad = lane >> 4;

  floatx4 acc[4][4];
#pragma unroll
  for (int i = 0; i < 4; ++i)
#pragma unroll
    for (int j = 0; j < 4; ++j) acc[i][j] = (floatx4)0.f;

  const int arow = t >> 2, akl = (t & 3) * 8;  // A staging coords
  const int wcol = t;                          // W staging coord
  const int wmat = wcol >> 7, wn = wcol & 127;

  for (int p = 0; p < 4; ++p) {
    // --- stage A (64 rows x 32 k fp32 -> bf16 hi/lo), read A exactly once ---
    {
      const int grow = row0 + arow;
      const bool ok = grow < n;
      const float* gp = A + (size_t)grow * D + p * 32 + akl;
      float4 v0 = make_float4(0.f, 0.f, 0.f, 0.f), v1 = v0;
      if (ok) {
        v0 = *(const float4*)gp;
        v1 = *(const float4*)(gp + 4);
      }
      ushort h0, l0, h1, l1, h2, l2, h3, l3;
      const int a = arow * 40 + akl;
      bf16split(v0.x, h0, l0); bf16split(v0.y, h1, l1);
      bf16split(v0.z, h2, l2); bf16split(v0.w, h3, l3);
      *(ushort4*)&Ah[a] = make_ushort4(h0, h1, h2, h3);
      *(ushort4*)&Al[a] = make_ushort4(l0, l1, l2, l3);
      bf16split(v1.x, h0, l0); bf16split(v1.y, h1, l1);
      bf16split(v1.z, h2, l2); bf16split(v1.w, h3, l3);
      *(ushort4*)&Ah[a + 4] = make_ushort4(h0, h1, h2, h3);
      *(ushort4*)&Al[a + 4] = make_ushort4(l0, l1, l2, l3);
    }
    // --- stage W' slab (256 cols x 32 k bf16 hi/lo from precomputed wt) ---
    {
      const ushort* gh = wt + (size_t)wmat * 32768 + (size_t)wn * 128 + p * 32;
      const ushort* gl = gh + 16384;
      const int a = wcol * 40;
#pragma unroll
      for (int c = 0; c < 4; ++c) {
        *(uint4*)&Wh[a + 8 * c] = *(const uint4*)(gh + 8 * c);
        *(uint4*)&Wl[a + 8 * c] = *(const uint4*)(gl + 8 * c);
      }
    }
    __syncthreads();
    short8 a_h[4], a_l[4];
#pragma unroll
    for (int i = 0; i < 4; ++i) {
      const int r = (i * 16 + m) * 40 + quad * 8;
      a_h[i] = *(const short8*)&Ah[r];
      a_l[i] = *(const short8*)&Al[r];
    }
#pragma unroll
    for (int j = 0; j < 4; ++j) {
      const int r = (w * 64 + j * 16 + m) * 40 + quad * 8;
      const short8 b_h = *(const short8*)&Wh[r];
      const short8 b_l = *(const short8*)&Wl[r];
#pragma unroll
      for (int i = 0; i < 4; ++i) {
        floatx4 c = acc[i][j];
        c = __builtin_amdgcn_mfma_f32_16x16x32_bf16(a_h[i], b_h, c, 0, 0, 0);
        c = __builtin_amdgcn_mfma_f32_16x16x32_bf16(a_h[i], b_l, c, 0, 0, 0);
        c = __builtin_amdgcn_mfma_f32_16x16x32_bf16(a_l[i], b_h, c, 0, 0, 0);
        acc[i][j] = c;
      }
    }
    __syncthreads();
  }

  // --- epilogue: C/D layout col=lane&15, row=quad*4+reg; branch is wave-uniform ---
  if (w < 2) {
    float bb[4], gg[4];
#pragma unroll
    for (int j = 0; j < 4; ++j) {
      const int col = w * 64 + j * 16 + m;
      bb[j] = b1[col];
      gg[j] = gvec[col];
    }
#pragma unroll
    for (int i = 0; i < 4; ++i)
#pragma unroll
      for (int pp = 0; pp < 4; ++pp) {
        const int rg = row0 + i * 16 + quad * 4 + pp;
        if (rg >= n) continue;
#pragma unroll
        for (int j = 0; j < 4; ++j) {
          const int col = w * 64 + j * 16 + m;
          outH[(size_t)rg * D + col] = acc[i][j][pp] + bb[j] + gg[j];
        }
      }
  } else {
    float bb[4];
#pragma unroll
    for (int j = 0; j < 4; ++j) bb[j] = b2[(w - 2) * 64 + j * 16 + m];
#pragma unroll
    for (int i = 0; i < 4; ++i)
#pragma unroll
      for (int pp = 0; pp < 4; ++pp) {
        const int rg = row0 + i * 16 + quad * 4 + pp;
        if (rg >= n) continue;
        const float sc = rsqrtf(fmaxf((float)cnt_send[rg], 1.f));
#pragma unroll
        for (int j = 0; j < 4; ++j) {
          const int col = (w - 2) * 64 + j * 16 + m;
          conv[(size_t)rg * D + col] = (acc[i][j][pp] + bb[j]) * sc;
        }
      }
  }
}

// K5: pull aggregation + fused epilogue, v3.
// Half-wave (32 lanes) per row, float4/lane. TWO rows processed concurrently
// per half-wave: both rows' srt index loads issue together, then 16 independent
// 16B gathers are in flight per lane (masked single-shot of 8 covers
// P(dg<=8)=0.81 of Poisson(6.4) rows; rare dg>8 tail handled in a short loop).
__global__ __launch_bounds__(256) void k_agg_finalize(
    const float* __restrict__ conv, const int* __restrict__ off,
    const int* __restrict__ cnt_recv, const int* __restrict__ srt,
    const float* __restrict__ nodes, float* __restrict__ h,
    float* __restrict__ an, int n) {
  __shared__ float anl[8][D];
  const int hw = threadIdx.x >> 5;
  const int ln = threadIdx.x & 31;
  const int ghw = blockIdx.x * 8 + hw;
  const int nhw = gridDim.x * 8;
  const int c0 = ln * 4;

  float a0 = 0.f, a1 = 0.f, a2 = 0.f, a3 = 0.f;

  for (int r0 = ghw; r0 < n; r0 += 2 * nhw) {
    const int r1 = r0 + nhw;
    const bool has1 = r1 < n;
    const int dg0 = cnt_recv[r0];
    const int o0 = off[r0];
    const int dg1 = has1 ? cnt_recv[r1] : 0;
    const int o1 = has1 ? off[r1] : o0;

    // issue both rows' index loads, then all gathers
    int idx0[8], idx1[8];
    float mk0[8], mk1[8];
#pragma unroll
    for (int j = 0; j < 8; ++j) {
      const bool v0 = j < dg0;
      idx0[j] = srt[o0 + (v0 ? j : 0)];
      mk0[j] = v0 ? 1.f : 0.f;
      const bool v1 = j < dg1;
      idx1[j] = srt[o1 + (v1 ? j : 0)];
      mk1[j] = v1 ? 1.f : 0.f;
    }
    const float4 h10 = *(const float4*)(h + (size_t)r0 * D + c0);
    const float4 nd0 = *(const float4*)(nodes + (size_t)r0 * D + c0);
    float4 c0v[8], c1v[8];
#pragma unroll
    for (int j = 0; j < 8; ++j)
      c0v[j] = *(const float4*)(conv + (size_t)idx0[j] * D + c0);
#pragma unroll
    for (int j = 0; j < 8; ++j)
      c1v[j] = *(const float4*)(conv + (size_t)idx1[j] * D + c0);

    float sx0 = 0.f, sy0 = 0.f, sz0 = 0.f, sw0 = 0.f;
    float sx1 = 0.f, sy1 = 0.f, sz1 = 0.f, sw1 = 0.f;
#pragma unroll
    for (int j = 0; j < 8; ++j) {
      sx0 = fmaf(mk0[j], c0v[j].x, sx0);
      sy0 = fmaf(mk0[j], c0v[j].y, sy0);
      sz0 = fmaf(mk0[j], c0v[j].z, sz0);
      sw0 = fmaf(mk0[j], c0v[j].w, sw0);
      sx1 = fmaf(mk1[j], c1v[j].x, sx1);
      sy1 = fmaf(mk1[j], c1v[j].y, sy1);
      sz1 = fmaf(mk1[j], c1v[j].z, sz1);
      sw1 = fmaf(mk1[j], c1v[j].w, sw1);
    }
    // rare tail: degree > 8 (P ~ 0.19 per row)
    for (int i = 8; i < dg0; ++i) {
      const int s = srt[o0 + i];
      const float4 c = *(const float4*)(conv + (size_t)s * D + c0);
      sx0 += c.x; sy0 += c.y; sz0 += c.z; sw0 += c.w;
    }
    for (int i = 8; i < dg1; ++i) {
      const int s = srt[o1 + i];
      const float4 c = *(const float4*)(conv + (size_t)s * D + c0);
      sx1 += c.x; sy1 += c.y; sz1 += c.z; sw1 += c.w;
    }

    {
      const float sc = rsqrtf(fmaxf((float)dg0, 1.f));
      const float x0 = fmaxf(h10.x + sx0 * sc, 0.f) + nd0.x;
      const float x1 = fmaxf(h10.y + sy0 * sc, 0.f) + nd0.y;
      const float x2 = fmaxf(h10.z + sz0 * sc, 0.f) + nd0.z;
      const float x3 = fmaxf(h10.w + sw0 * sc, 0.f) + nd0.w;
      *(float4*)(h + (size_t)r0 * D + c0) = make_float4(x0, x1, x2, x3);
      a0 += x0; a1 += x1; a2 += x2; a3 += x3;
    }
    if (has1) {
      const float4 h11 = *(const float4*)(h + (size_t)r1 * D + c0);
      const float4 nd1 = *(const float4*)(nodes + (size_t)r1 * D + c0);
      const float sc = rsqrtf(fmaxf((float)dg1, 1.f));
      const float x0 = fmaxf(h11.x + sx1 * sc, 0.f) + nd1.x;
      const float x1 = fmaxf(h11.y + sy1 * sc, 0.f) + nd1.y;
      const float x2 = fmaxf(h11.z + sz1 * sc, 0.f) + nd1.z;
      const float x3 = fmaxf(h11.w + sw1 * sc, 0.f) + nd1.w;
      *(float4*)(h + (size_t)r1 * D + c0) = make_float4(x0, x1, x2, x3);
      a0 += x0; a1 += x1; a2 += x2; a3 += x3;
    }
  }
  anl[hw][c0 + 0] = a0;
  anl[hw][c0 + 1] = a1;
  anl[hw][c0 + 2] = a2;
  anl[hw][c0 + 3] = a3;
  __syncthreads();
  if (threadIdx.x < D) {
    float s = 0.f;
#pragma unroll
    for (int k = 0; k < 8; ++k) s += anl[k][threadIdx.x];
    atomicAdd(an + threadIdx.x, s);
  }
}

// K6: g_new = globals + relu(concat([an, globals]) @ Wg + bg), 2-way k-split
__global__ void k_gupdate(const float* __restrict__ an, const float* __restrict__ g,
                          const float* __restrict__ Wg, const float* __restrict__ bg,
                          float* __restrict__ gout) {
  __shared__ float part[256];
  const int j = threadIdx.x & 127, half = threadIdx.x >> 7;
  float acc = 0.f;
  if (half == 0) {
    for (int k = 0; k < D; ++k) acc = fmaf(an[k], Wg[k * D + j], acc);
  } else {
    for (int k = 0; k < D; ++k) acc = fmaf(g[k], Wg[(D + k) * D + j], acc);
  }
  part[threadIdx.x] = acc;
  __syncthreads();
  if (threadIdx.x < D)
    gout[j] = g[j] + fmaxf(bg[j] + part[j] + part[j + 128], 0.f);
}

extern "C" void kernel_launch(void* const* d_in, const int* in_sizes, int n_in,
                              void* d_out, int out_size, void* d_ws, size_t ws_size,
                              hipStream_t stream) {
  const float* nodes = (const float*)d_in[0];
  const float* globals_ = (const float*)d_in[1];
  const int* senders = (const int*)d_in[2];
  const int* receivers = (const int*)d_in[3];
  const float* W1_w = (const float*)d_in[4];
  const float* W1_b = (const float*)d_in[5];
  const float* W2_w = (const float*)d_in[6];
  const float* W2_b = (const float*)d_in[7];
  const float* W3_w = (const float*)d_in[8];
  const float* W3_b = (const float*)d_in[9];
  const float* Wg_w = (const float*)d_in[10];
  const float* Wg_b = (const float*)d_in[11];
  const int N = in_sizes[0] / D;
  const int E = in_sizes[2];
  const int nb = (N + SCH - 1) / SCH;

  float* h = (float*)d_out;
  float* gout = h + (size_t)N * D;

  float* ws = (float*)d_ws;
  float* conv = ws;                            // N*D floats
  int* cnt_send = (int*)(ws + (size_t)N * D);  // N
  int* cnt_recv = cnt_send + N;                // N
  int* off = cnt_recv + N;                     // N
  int* cursor = off + N;                       // N (dead after k_fill -> wt)
  int* srt = cursor + N;                       // E
  float* gvec = (float*)(srt + E);             // D
  float* an = gvec + D;                        // D
  int* bsum = (int*)(an + D);                  // nb
  int* bbase = bsum + 256;                     // nb
  ushort* wt = (ushort*)cursor;                // 128 KB, reused after k_fill

  (void)hipMemsetAsync(cnt_send, 0, 2 * (size_t)N * sizeof(int), stream);

  hipLaunchKernelGGL(k_gproj, dim3(2), dim3(256), 0, stream, globals_, W3_w, W3_b,
                     gvec, an);
  hipLaunchKernelGGL(k_degrees, dim3((E + 255) / 256), dim3(256), 0, stream,
                     senders, receivers, cnt_send, cnt_recv, E);
  hipLaunchKernelGGL(k_scanA, dim3(nb), dim3(256), 0, stream, cnt_recv, bsum, N);
  hipLaunchKernelGGL(k_scanB, dim3(1), dim3(256), 0, stream, bsum, bbase, nb);
  hipLaunchKernelGGL(k_scanC, dim3(nb), dim3(256), 0, stream, cnt_recv, bbase,
                     off, cursor, N);
  hipLaunchKernelGGL(k_fill, dim3((E + 255) / 256), dim3(256), 0, stream,
                     senders, receivers, cursor, srt, E);
  hipLaunchKernelGGL(k_wsplit, dim3(128), dim3(256), 0, stream, W1_w, W2_w, wt);
  hipLaunchKernelGGL(k_gemm, dim3((N + 63) / 64), dim3(256), 0, stream,
                     nodes, wt, W1_b, W2_b, gvec, cnt_send, h, conv, N);
  hipLaunchKernelGGL(k_agg_finalize, dim3(2048), dim3(256), 0, stream,
                     conv, off, cnt_recv, srt, nodes, h, an, N);
  hipLaunchKernelGGL(k_gupdate, dim3(1), dim3(256), 0, stream, an, globals_,
                     Wg_w, Wg_b, gout);
}